// Round 19
// baseline (112.069 us; speedup 1.0000x reference)
//
#include <hip/hip_runtime.h>
#include <stdint.h>

typedef __attribute__((ext_vector_type(8))) short short8;
typedef __attribute__((ext_vector_type(4))) float f32x4;
typedef __attribute__((ext_vector_type(16))) float f32x16;
typedef __attribute__((ext_vector_type(4))) unsigned short ushort4v;
typedef __attribute__((ext_vector_type(2))) int int2v;

#define BB 2
#define SS 2048
#define NXDIM 1024
#define NHEADS 16
#define HDIM 64

__device__ __forceinline__ unsigned short f2bf(float f){
  unsigned int u = __float_as_uint(f);
  u += 0x7fffu + ((u >> 16) & 1u);
  return (unsigned short)(u >> 16);
}

__device__ __forceinline__ void gload_lds16(const void* g, void* l){
  __builtin_amdgcn_global_load_lds((const __attribute__((address_space(1))) void*)g,
                                   (__attribute__((address_space(3))) void*)l, 16, 0, 0);
}

__device__ __forceinline__ unsigned cvt_pk_bf16(float lo, float hi){
  unsigned r;
  asm("v_cvt_pk_bf16_f32 %0, %1, %2" : "=v"(r) : "v"(lo), "v"(hi));
  return r;
}

__device__ __forceinline__ int2v ds_tr_b16(unsigned addr){
  int2v r;
  asm volatile("ds_read_b64_tr_b16 %0, %1" : "=v"(r) : "v"(addr));
  return r;
}

// permlane32_swap (SSA builtin, no operand aliasing)
__device__ __forceinline__ int2v plswap(int a, int b){
  return __builtin_amdgcn_permlane32_swap(a, b, false, false);
}
__device__ __forceinline__ float plmax(float x){
  int2v r = plswap(__float_as_int(x), __float_as_int(x));
  return fmaxf(__int_as_float(r.x), __int_as_float(r.y));
}
__device__ __forceinline__ float pladd(float x){
  int2v r = plswap(__float_as_int(x), __float_as_int(x));
  return __int_as_float(r.x) + __int_as_float(r.y);
}

// ---------------- fused prep: x f32->bf16 + both weight transposes ----------------
__global__ __launch_bounds__(256) void prep_k(const float* __restrict__ x,
                                              unsigned short* __restrict__ xb,
                                              const float* __restrict__ wa,
                                              unsigned short* __restrict__ waT,
                                              const float* __restrict__ wp,
                                              unsigned short* __restrict__ wpT){
  __shared__ float t[32][33];
  int bid = blockIdx.x;
  if (bid < 4096){
    const int i = bid*256 + (int)threadIdx.x;
    float4 v = ((const float4*)x)[i];
    ushort4v r = { f2bf(v.x), f2bf(v.y), f2bf(v.z), f2bf(v.w) };
    ((ushort4v*)xb)[i] = r;
    return;
  }
  bid -= 4096;
  const int by = (bid >> 7) * 32;
  int bxi = bid & 127;
  const bool second = bxi >= 96;
  const float* in = second ? wp : wa;
  unsigned short* out = second ? wpT : waT;
  const int C = second ? 1024 : 3072;
  const int R = 1024;
  const int bx = (second ? (bxi - 96) : bxi) * 32;
  const int tx = threadIdx.x & 31, ty = threadIdx.x >> 5;
  #pragma unroll
  for (int i = ty; i < 32; i += 8)
    t[i][tx] = in[(size_t)(by + i) * C + bx + tx];
  __syncthreads();
  #pragma unroll
  for (int i = ty; i < 32; i += 8)
    out[(size_t)(bx + i) * R + by + tx] = f2bf(t[tx][i]);
}

// ---------------- bf16 GEMM 64² tile — gemm2 (R16-verified) ----------
__global__ __launch_bounds__(256) void gemm2_64_k(const unsigned short* __restrict__ A,
                                                  const unsigned short* __restrict__ BT,
                                                  const float* __restrict__ bias,
                                                  float* __restrict__ Cout,
                                                  int M, int N, int K)
{
  __shared__ unsigned short As[64*32];
  __shared__ unsigned short Bs[64*32];
  const int tid = threadIdx.x;
  const int w = tid >> 6, lane = tid & 63;
  const int l15 = lane & 15, g = lane >> 4;
  const int wr = w >> 1, wc = w & 1;
  const int m0 = blockIdx.y * 64, n0 = blockIdx.x * 64;

  f32x4 acc[2][2];
  #pragma unroll
  for (int m=0;m<2;m++)
    #pragma unroll
    for (int n=0;n<2;n++) acc[m][n] = (f32x4){0.f,0.f,0.f,0.f};

  const int srow_in = lane >> 2;
  const int scol = (lane & 3) * 8;

  for (int k0 = 0; k0 < K; k0 += 32){
    __syncthreads();
    gload_lds16(A  + (size_t)(m0 + w*16 + srow_in) * K + (k0 + scol), &As[(w*16)*32]);
    gload_lds16(BT + (size_t)(n0 + w*16 + srow_in) * K + (k0 + scol), &Bs[(w*16)*32]);
    __syncthreads();

    short8 af[2], bf[2];
    #pragma unroll
    for (int m=0;m<2;m++) af[m] = *(const short8*)&As[(wr*32 + m*16 + l15)*32 + g*8];
    #pragma unroll
    for (int n=0;n<2;n++) bf[n] = *(const short8*)&Bs[(wc*32 + n*16 + l15)*32 + g*8];
    #pragma unroll
    for (int m=0;m<2;m++)
      #pragma unroll
      for (int n=0;n<2;n++)
        acc[m][n] = __builtin_amdgcn_mfma_f32_16x16x32_bf16(af[m], bf[n], acc[m][n], 0, 0, 0);
  }

  const int crow0 = m0 + wr*32;
  const int ccol0 = n0 + wc*32;
  #pragma unroll
  for (int n=0;n<2;n++){
    const int col = ccol0 + n*16 + l15;
    const float bv = bias[col];
    #pragma unroll
    for (int m=0;m<2;m++){
      #pragma unroll
      for (int r=0;r<4;r++){
        const int row = crow0 + m*16 + g*4 + r;
        Cout[(size_t)row * N + col] = acc[m][n][r] + bv;
      }
    }
  }
}

// ---------------- bf16 GEMM 128x192, BK=32, 8 waves, 2 blocks/CU (TLP) ----------------
// C bf16 = A[M,K]*BT[N,K]^T + bias. 512 thr: wave (wm=w>>2, wn=w&3) owns 64x48
// (4 mf x 3 nf, 16x16x32 MFMA). LDS 48 KB: staging A[2][8KB]+B[2][12KB] = 40 KB,
// epilogue reuses as [128][192] bf16. Grid 16x32 = 512 blocks = 2/CU: the other
// block's compute hides this block's end-of-tile vmcnt drain (TLP, not pipelining).
// BK=32 swizzle pair (R14-verified): LDS[row][slot s] = G[row][8*(s^(row&3))..+8);
// read slot = g ^ (row&3). Staging: 16 rows/instr, srow=lane>>2, pre-XORed src col.
__global__ __launch_bounds__(512) void gemm128_k(const unsigned short* __restrict__ A,
                                                 const unsigned short* __restrict__ BT,
                                                 const float* __restrict__ bias,
                                                 unsigned short* __restrict__ Cout,
                                                 int M, int N, int K)
{
  __shared__ unsigned short lds[24576];           // 48 KB
  const int tid = threadIdx.x;
  const int w = tid >> 6, lane = tid & 63;
  const int l15 = lane & 15, g = lane >> 4;
  const int wm = w >> 2, wn = w & 3;
  const int m0 = blockIdx.y * 128, n0 = blockIdx.x * 192;

  f32x4 acc[4][3];
  #pragma unroll
  for (int m=0;m<4;m++)
    #pragma unroll
    for (int n=0;n<3;n++) acc[m][n] = (f32x4){0.f,0.f,0.f,0.f};

  const int srow_in = lane >> 2;                        // 0..15
  const int sscol   = 8 * ((lane & 3) ^ ((lane >> 2) & 3));  // pre-XORed source col

  // LDS layout (ushort units): As[bi] at bi*4096 (8 KB), Bs[bi] at 8192 + bi*6144 (12 KB)
  auto stage = [&](int bi, int kt){
    const int k0 = kt * 32;
    unsigned short* Ad = lds + bi*4096;
    unsigned short* Bd = lds + 8192 + bi*6144;
    // A: 8 chunks of 16 rows, wave w does chunk w
    gload_lds16(A + (size_t)(m0 + w*16 + srow_in) * K + (k0 + sscol), Ad + (w*16)*32);
    // B: 12 chunks of 16 rows, wave w does chunk w; waves 0-3 also chunk 8+w
    gload_lds16(BT + (size_t)(n0 + w*16 + srow_in) * K + (k0 + sscol), Bd + (w*16)*32);
    if (w < 4)
      gload_lds16(BT + (size_t)(n0 + (8+w)*16 + srow_in) * K + (k0 + sscol), Bd + ((8+w)*16)*32);
  };

  const int nt = K >> 5;                         // 32
  stage(0, 0);
  asm volatile("s_waitcnt vmcnt(0)" ::: "memory");
  __syncthreads();

  for (int t = 0; t < nt; ++t){
    const int bi = t & 1;
    if (t + 1 < nt) stage(bi^1, t+1);            // phase-0 issue of next tile

    const char* Ab = (const char*)(lds + bi*4096);
    const char* Bb = (const char*)(lds + 8192 + bi*6144);

    short8 af[4], bf[3];
    #pragma unroll
    for (int m=0;m<4;m++){
      const int row = wm*64 + m*16 + l15;
      af[m] = *(const short8*)(Ab + row*64 + 16*(g ^ (row&3)));
    }
    #pragma unroll
    for (int n=0;n<3;n++){
      const int row = wn*48 + n*16 + l15;
      bf[n] = *(const short8*)(Bb + row*64 + 16*(g ^ (row&3)));
    }
    asm volatile("s_waitcnt lgkmcnt(0)" ::: "memory");
    __builtin_amdgcn_sched_barrier(0);

    __builtin_amdgcn_s_setprio(1);
    #pragma unroll
    for (int m=0;m<4;m++)
      #pragma unroll
      for (int n=0;n<3;n++)
        acc[m][n] = __builtin_amdgcn_mfma_f32_16x16x32_bf16(af[m], bf[n], acc[m][n], 0, 0, 0);
    __builtin_amdgcn_s_setprio(0);

    asm volatile("s_waitcnt vmcnt(0)" ::: "memory");
    __syncthreads();
  }

  // coalesced epilogue: acc -> LDS [128][192] bf16 -> 16B/lane stores
  unsigned short* ct = lds;
  #pragma unroll
  for (int n=0;n<3;n++){
    const int col = wn*48 + n*16 + l15;
    const float bv = bias[n0 + col];
    #pragma unroll
    for (int m=0;m<4;m++){
      #pragma unroll
      for (int r=0;r<4;r++)
        ct[(wm*64 + m*16 + g*4 + r)*192 + col] = f2bf(acc[m][n][r] + bv);
    }
  }
  __syncthreads();
  #pragma unroll
  for (int u = 0; u < 6; ++u){
    const int idx = u*512 + tid;                 // short8 units, 3072 total
    const int row = idx / 24, sl = idx % 24;
    *(short8*)(Cout + (size_t)(m0 + row) * N + n0 + sl*8) = *(const short8*)&ct[row*192 + sl*8];
  }
}

// ---------------- causal flash attention (R13/R16-exact, 48 us — DO NOT RESTRUCTURE) ----
__global__ __launch_bounds__(512) void attn_k(const unsigned short* __restrict__ qkv,
                                              unsigned short* __restrict__ aout)
{
  const int xy = ((int)blockIdx.x + (int)blockIdx.y) & 15;
  const int qb = blockIdx.z ? xy : (15 - xy);
  const int h = blockIdx.y, b = blockIdx.z;
  const int tid = threadIdx.x;
  const int w = tid >> 6, lane = tid & 63;
  const int l31 = lane & 31, hi = lane >> 5;
  const int qw = w >> 1, p = w & 1;

  __shared__ unsigned short lds[32768];
  unsigned short* Ksb = lds;
  unsigned short* Vsb = lds + 16384;

  const size_t rs = 3 * NXDIM;
  const unsigned short* Qg = qkv + (size_t)b * SS * rs + h * HDIM;
  const unsigned short* Kg = Qg + NXDIM;
  const unsigned short* Vg = Qg + 2 * NXDIM;

  const int q0w = qb*128 + qw*32;
  const int q   = q0w + l31;
  const int qw_hi = q0w + 31;

  short8 qf[4];
  #pragma unroll
  for (int c=0;c<4;c++)
    qf[c] = *(const short8*)(Qg + (size_t)q * rs + c*16 + 8*hi);

  f32x16 O0, O1;
  #pragma unroll
  for (int r=0;r<16;r++){ O0[r]=0.f; O1[r]=0.f; }
  float m_run = -1e30f, l_run = 0.f;
  const float SC2 = 0.125f * 1.44269504089f;
  const float THRR = 44.36f;

  const int krow_in = lane >> 3;
  const int kcol    = 8 * ((lane & 7) ^ (lane >> 3));
  const int v_d     = ((lane >> 3) & 3) * 16 + 8 * (lane & 1);
  const unsigned vtr_base = (unsigned)(size_t)Vsb + 8u*(unsigned)lane + 768u*(unsigned)hi;

  auto stage = [&](int bi, int tt){
    unsigned short* Kd = Ksb + (p*2 + bi)*4096;
    unsigned short* Vd = Vsb + (p*2 + bi)*4096;
    #pragma unroll
    for (int j=0;j<2;j++){
      const int ch = qw*2 + j;
      const int krow = tt*64 + ch*8 + krow_in;
      gload_lds16(Kg + (size_t)krow * rs + kcol, Kd + ch*512);
      const int vkv = tt*64 + (ch*2 + hi)*4 + ((lane>>1)&3);
      gload_lds16(Vg + (size_t)vkv * rs + v_d, Vd + ch*512);
    }
  };

  const int tmax = 2*qb + 1;
  stage(0, p);
  __syncthreads();
  int cur = 0;

  for (int t = p; t <= tmax; t += 2){
    if (t + 2 <= tmax) stage(cur^1, t+2);

    const char* Kb = (const char*)(Ksb + (p*2 + cur)*4096);
    const unsigned vb = vtr_base + (unsigned)((p*2 + cur)*8192);

    #pragma unroll
    for (int kvs=0;kvs<2;kvs++){
      const int kv_lo = t*64 + kvs*32;
      if (kv_lo > qw_hi) continue;

      f32x16 S;
      #pragma unroll
      for (int r=0;r<16;r++) S[r] = 0.f;
      __builtin_amdgcn_s_setprio(1);
      #pragma unroll
      for (int c=0;c<4;c++){
        const int row = kvs*32 + l31;
        short8 kf = *(const short8*)(Kb + row*128 + ((c*32 + 16*hi) ^ ((row&7)<<4)));
        S = __builtin_amdgcn_mfma_f32_32x32x16_bf16(kf, qf[c], S, 0, 0, 0);
      }
      __builtin_amdgcn_s_setprio(0);

      int2v tv[8];
      #pragma unroll
      for (int c=0;c<2;c++)
        #pragma unroll
        for (int dh=0;dh<2;dh++)
          #pragma unroll
          for (int eb=0;eb<2;eb++)
            tv[c*4+dh*2+eb] = ds_tr_b16(vb + (unsigned)((kvs*8 + c*4 + eb)*512 + dh*256));

      float mA=-1e30f, mB=-1e30f, mC=-1e30f, mD=-1e30f;
      if (kv_lo + 31 > q0w){
        #pragma unroll
        for (int r=0;r<16;r+=4){
          const int kvb = kv_lo + 8*(r>>2) + 4*hi;
          float s0 = (kvb+0 <= q) ? S[r+0] : -1e30f;
          float s1 = (kvb+1 <= q) ? S[r+1] : -1e30f;
          float s2 = (kvb+2 <= q) ? S[r+2] : -1e30f;
          float s3 = (kvb+3 <= q) ? S[r+3] : -1e30f;
          S[r+0]=s0; S[r+1]=s1; S[r+2]=s2; S[r+3]=s3;
          mA = fmaxf(mA, s0); mB = fmaxf(mB, s1); mC = fmaxf(mC, s2); mD = fmaxf(mD, s3);
        }
      } else {
        #pragma unroll
        for (int r=0;r<16;r+=4){
          mA = fmaxf(mA, S[r+0]); mB = fmaxf(mB, S[r+1]);
          mC = fmaxf(mC, S[r+2]); mD = fmaxf(mD, S[r+3]);
        }
      }
      float mx = fmaxf(fmaxf(mA,mB), fmaxf(mC,mD));
      mx = plmax(mx);

      if (!__all(mx <= m_run + THRR)){
        const float m_new = fmaxf(m_run, mx);
        const float corr = __builtin_exp2f((m_run - m_new) * SC2);
        m_run = m_new;
        l_run *= corr;
        #pragma unroll
        for (int r=0;r<16;r++){ O0[r] *= corr; O1[r] *= corr; }
      }
      const float msc = m_run * SC2;

      float lA=0.f, lB=0.f, lC=0.f, lD=0.f;
      #pragma unroll
      for (int r=0;r<16;r+=4){
        float p0=__builtin_exp2f(__builtin_fmaf(S[r+0],SC2,-msc));
        float p1=__builtin_exp2f(__builtin_fmaf(S[r+1],SC2,-msc));
        float p2=__builtin_exp2f(__builtin_fmaf(S[r+2],SC2,-msc));
        float p3=__builtin_exp2f(__builtin_fmaf(S[r+3],SC2,-msc));
        S[r+0]=p0; S[r+1]=p1; S[r+2]=p2; S[r+3]=p3;
        lA+=p0; lB+=p1; lC+=p2; lD+=p3;
      }
      float ls = (lA+lB) + (lC+lD);
      ls = pladd(ls);
      l_run += ls;

      unsigned pk[8];
      #pragma unroll
      for (int i=0;i<8;i++) pk[i] = cvt_pk_bf16(S[2*i], S[2*i+1]);
      short8 pfrag[2];
      #pragma unroll
      for (int c=0;c<2;c++){
        int2v r0 = plswap((int)pk[4*c+0], (int)pk[4*c+2]);
        int2v r1 = plswap((int)pk[4*c+1], (int)pk[4*c+3]);
        union { unsigned u[4]; short8 s; } pw;
        pw.u[0] = (unsigned)r0.x; pw.u[1] = (unsigned)r1.x;
        pw.u[2] = (unsigned)r0.y; pw.u[3] = (unsigned)r1.y;
        pfrag[c] = pw.s;
      }

      asm volatile("s_waitcnt lgkmcnt(0)" ::: "memory");
      __builtin_amdgcn_sched_barrier(0);

      __builtin_amdgcn_s_setprio(1);
      #pragma unroll
      for (int c=0;c<2;c++){
        union { int2v t[2]; short8 s; } v0, v1;
        v0.t[0] = tv[c*4+0]; v0.t[1] = tv[c*4+1];
        v1.t[0] = tv[c*4+2]; v1.t[1] = tv[c*4+3];
        O0 = __builtin_amdgcn_mfma_f32_32x32x16_bf16(v0.s, pfrag[c], O0, 0, 0, 0);
        O1 = __builtin_amdgcn_mfma_f32_32x32x16_bf16(v1.s, pfrag[c], O1, 0, 0, 0);
      }
      __builtin_amdgcn_s_setprio(0);
    }

    __syncthreads();
    cur ^= 1;
  }

  float* sm = (float*)lds + qw * (64*34);
  if (p){
    #pragma unroll
    for (int r=0;r<16;r++){ sm[lane*34 + r] = O0[r]; sm[lane*34 + 16 + r] = O1[r]; }
    sm[lane*34 + 32] = m_run;
    sm[lane*34 + 33] = l_run;
  }
  __syncthreads();
  if (!p){
    const float m1 = sm[lane*34 + 32], l1 = sm[lane*34 + 33];
    const float mm = fmaxf(m_run, m1);
    const float c0 = __builtin_exp2f((m_run - mm) * SC2);
    const float c1 = __builtin_exp2f((m1 - mm) * SC2);
    const float inv = 1.f / (l_run*c0 + l1*c1);
    unsigned short* dst = aout + ((size_t)b*SS + q) * NXDIM + h*HDIM;
    #pragma unroll
    for (int g4=0; g4<4; g4++){
      ushort4v a0, a1;
      #pragma unroll
      for (int i=0;i<4;i++){
        a0[i] = f2bf((O0[4*g4+i]*c0 + sm[lane*34 + 4*g4+i]*c1) * inv);
        a1[i] = f2bf((O1[4*g4+i]*c0 + sm[lane*34 + 16 + 4*g4+i]*c1) * inv);
      }
      *(ushort4v*)(dst + 8*g4 + 4*hi)      = a0;
      *(ushort4v*)(dst + 32 + 8*g4 + 4*hi) = a1;
    }
  }
}

extern "C" void kernel_launch(void* const* d_in, const int* in_sizes, int n_in,
                              void* d_out, int out_size, void* d_ws, size_t ws_size,
                              hipStream_t stream){
  (void)in_sizes; (void)n_in; (void)out_size; (void)ws_size;
  const float* x      = (const float*)d_in[0];   // [2,2048,1024]
  const float* w_attn = (const float*)d_in[1];   // [1024,3072]
  const float* b_attn = (const float*)d_in[2];   // [3072]
  const float* w_proj = (const float*)d_in[3];   // [1024,1024]
  const float* b_proj = (const float*)d_in[4];   // [1024]
  float* out = (float*)d_out;                    // [2,2048,1024] f32

  unsigned short* xb   = (unsigned short*)d_ws;              // 4096x1024 bf16
  unsigned short* waT  = xb  + (size_t)4096*1024;            // 3072x1024 bf16 (W_attn^T)
  unsigned short* wpT  = waT + (size_t)3072*1024;            // 1024x1024 bf16 (W_proj^T)
  unsigned short* qkv  = wpT + (size_t)1024*1024;            // 4096x3072 bf16
  unsigned short* aout = qkv + (size_t)4096*3072;            // 4096x1024 bf16

  prep_k<<<8192, 256, 0, stream>>>(x, xb, w_attn, waT, w_proj, wpT);
  gemm128_k<<<dim3(3072/192, 4096/128), 512, 0, stream>>>(xb, waT, b_attn, qkv, 4096, 3072, 1024);
  attn_k<<<dim3(SS/128, NHEADS, BB), 512, 0, stream>>>(qkv, aout);
  gemm2_64_k<<<dim3(1024/64, 4096/64), 256, 0, stream>>>(aout, wpT, b_proj, out, 4096, 1024, 1024);
}

// Round 20
// 107.386 us; speedup vs baseline: 1.0436x; 1.0436x over previous
//
#include <hip/hip_runtime.h>
#include <stdint.h>

typedef __attribute__((ext_vector_type(8))) short short8;
typedef __attribute__((ext_vector_type(4))) float f32x4;
typedef __attribute__((ext_vector_type(16))) float f32x16;
typedef __attribute__((ext_vector_type(4))) unsigned short ushort4v;
typedef __attribute__((ext_vector_type(2))) int int2v;

#define BB 2
#define SS 2048
#define NXDIM 1024
#define NHEADS 16
#define HDIM 64

__device__ __forceinline__ unsigned short f2bf(float f){
  unsigned int u = __float_as_uint(f);
  u += 0x7fffu + ((u >> 16) & 1u);
  return (unsigned short)(u >> 16);
}

__device__ __forceinline__ void gload_lds16(const void* g, void* l){
  __builtin_amdgcn_global_load_lds((const __attribute__((address_space(1))) void*)g,
                                   (__attribute__((address_space(3))) void*)l, 16, 0, 0);
}

__device__ __forceinline__ unsigned cvt_pk_bf16(float lo, float hi){
  unsigned r;
  asm("v_cvt_pk_bf16_f32 %0, %1, %2" : "=v"(r) : "v"(lo), "v"(hi));
  return r;
}

__device__ __forceinline__ int2v ds_tr_b16(unsigned addr){
  int2v r;
  asm volatile("ds_read_b64_tr_b16 %0, %1" : "=v"(r) : "v"(addr));
  return r;
}

// permlane32_swap (SSA builtin, no operand aliasing)
__device__ __forceinline__ int2v plswap(int a, int b){
  return __builtin_amdgcn_permlane32_swap(a, b, false, false);
}
__device__ __forceinline__ float plmax(float x){
  int2v r = plswap(__float_as_int(x), __float_as_int(x));
  return fmaxf(__int_as_float(r.x), __int_as_float(r.y));
}
__device__ __forceinline__ float pladd(float x){
  int2v r = plswap(__float_as_int(x), __float_as_int(x));
  return __int_as_float(r.x) + __int_as_float(r.y);
}

// ---------------- fused prep: x f32->bf16 + both weight transposes ----------------
__global__ __launch_bounds__(256) void prep_k(const float* __restrict__ x,
                                              unsigned short* __restrict__ xb,
                                              const float* __restrict__ wa,
                                              unsigned short* __restrict__ waT,
                                              const float* __restrict__ wp,
                                              unsigned short* __restrict__ wpT){
  __shared__ float t[32][33];
  int bid = blockIdx.x;
  if (bid < 4096){
    const int i = bid*256 + (int)threadIdx.x;
    float4 v = ((const float4*)x)[i];
    ushort4v r = { f2bf(v.x), f2bf(v.y), f2bf(v.z), f2bf(v.w) };
    ((ushort4v*)xb)[i] = r;
    return;
  }
  bid -= 4096;
  const int by = (bid >> 7) * 32;
  int bxi = bid & 127;
  const bool second = bxi >= 96;
  const float* in = second ? wp : wa;
  unsigned short* out = second ? wpT : waT;
  const int C = second ? 1024 : 3072;
  const int R = 1024;
  const int bx = (second ? (bxi - 96) : bxi) * 32;
  const int tx = threadIdx.x & 31, ty = threadIdx.x >> 5;
  #pragma unroll
  for (int i = ty; i < 32; i += 8)
    t[i][tx] = in[(size_t)(by + i) * C + bx + tx];
  __syncthreads();
  #pragma unroll
  for (int i = ty; i < 32; i += 8)
    out[(size_t)(bx + i) * R + by + tx] = f2bf(t[tx][i]);
}

// ---------------- bf16 GEMM 64² tile — gemm2, double-buffered prefetch ----------
// 256 thr = 4 waves; wave (wr,wc) owns 32x32. 4 blocks/CU TLP + dbuf prefetch
// (stage t+1 before compute t; single __syncthreads per tile drains prefetch +
// protects buffer reuse — attn-verified pattern).
__global__ __launch_bounds__(256) void gemm2_64_k(const unsigned short* __restrict__ A,
                                                  const unsigned short* __restrict__ BT,
                                                  const float* __restrict__ bias,
                                                  float* __restrict__ Cout,
                                                  int M, int N, int K)
{
  __shared__ unsigned short As[2][64*32];
  __shared__ unsigned short Bs[2][64*32];
  const int tid = threadIdx.x;
  const int w = tid >> 6, lane = tid & 63;
  const int l15 = lane & 15, g = lane >> 4;
  const int wr = w >> 1, wc = w & 1;
  const int m0 = blockIdx.y * 64, n0 = blockIdx.x * 64;

  f32x4 acc[2][2];
  #pragma unroll
  for (int m=0;m<2;m++)
    #pragma unroll
    for (int n=0;n<2;n++) acc[m][n] = (f32x4){0.f,0.f,0.f,0.f};

  const int srow_in = lane >> 2;
  const int scol = (lane & 3) * 8;

  auto stage = [&](int bi, int kt){
    const int k0 = kt * 32;
    gload_lds16(A  + (size_t)(m0 + w*16 + srow_in) * K + (k0 + scol), &As[bi][(w*16)*32]);
    gload_lds16(BT + (size_t)(n0 + w*16 + srow_in) * K + (k0 + scol), &Bs[bi][(w*16)*32]);
  };

  const int nt = K >> 5;
  stage(0, 0);
  __syncthreads();
  int cur = 0;

  for (int t = 0; t < nt; ++t){
    if (t + 1 < nt) stage(cur^1, t+1);        // prefetch next tile

    short8 af[2], bf[2];
    #pragma unroll
    for (int m=0;m<2;m++) af[m] = *(const short8*)&As[cur][(wr*32 + m*16 + l15)*32 + g*8];
    #pragma unroll
    for (int n=0;n<2;n++) bf[n] = *(const short8*)&Bs[cur][(wc*32 + n*16 + l15)*32 + g*8];
    #pragma unroll
    for (int m=0;m<2;m++)
      #pragma unroll
      for (int n=0;n<2;n++)
        acc[m][n] = __builtin_amdgcn_mfma_f32_16x16x32_bf16(af[m], bf[n], acc[m][n], 0, 0, 0);

    __syncthreads();                          // drains prefetch + protects reuse
    cur ^= 1;
  }

  const int crow0 = m0 + wr*32;
  const int ccol0 = n0 + wc*32;
  #pragma unroll
  for (int n=0;n<2;n++){
    const int col = ccol0 + n*16 + l15;
    const float bv = bias[col];
    #pragma unroll
    for (int m=0;m<2;m++){
      #pragma unroll
      for (int r=0;r<4;r++){
        const int row = crow0 + m*16 + g*4 + r;
        Cout[(size_t)row * N + col] = acc[m][n][r] + bv;
      }
    }
  }
}

// ---------------- bf16 GEMM 256x192, BK=64, 8 waves (R16/R18-verified) ----------------
__global__ __launch_bounds__(512) void gemm256_k(const unsigned short* __restrict__ A,
                                                 const unsigned short* __restrict__ BT,
                                                 const float* __restrict__ bias,
                                                 unsigned short* __restrict__ Cout,
                                                 int M, int N, int K)
{
  __shared__ unsigned short lds[57344];            // As[2][16384] | Bs[2][12288]
  unsigned short* As0 = lds;
  unsigned short* Bs0 = lds + 32768;
  const int tid = threadIdx.x;
  const int w = tid >> 6, lane = tid & 63;
  const int l15 = lane & 15, g = lane >> 4;
  const int wm = w >> 2, wn = w & 3;
  const int m0 = blockIdx.y * 256, n0 = blockIdx.x * 192;

  f32x4 acc[8][3];
  #pragma unroll
  for (int m=0;m<8;m++)
    #pragma unroll
    for (int n=0;n<3;n++) acc[m][n] = (f32x4){0.f,0.f,0.f,0.f};

  const int srow = lane >> 3;
  const int scol = 8 * ((lane & 7) ^ (lane >> 3));

  auto stageA = [&](int bi, int k0, int j){
    const int r = w*32 + j*8 + srow;
    gload_lds16(A + (size_t)(m0 + r) * K + (k0 + scol), As0 + bi*16384 + (w*32 + j*8)*64);
  };
  auto stageB = [&](int bi, int k0, int j){
    const int r = w*24 + j*8 + srow;
    gload_lds16(BT + (size_t)(n0 + r) * K + (k0 + scol), Bs0 + bi*12288 + (w*24 + j*8)*64);
  };

  #pragma unroll
  for (int j=0;j<4;j++) stageA(0, 0, j);
  #pragma unroll
  for (int j=0;j<3;j++) stageB(0, 0, j);
  asm volatile("s_waitcnt vmcnt(0)" ::: "memory");
  __syncthreads();

  const int niter = K >> 6;
  int cur = 0;

  for (int t = 0; t < niter; ++t){
    const int k1 = (t+1) << 6;
    if (t+1 < niter){
      #pragma unroll
      for (int j=0;j<4;j++) stageA(cur^1, k1, j);
      #pragma unroll
      for (int j=0;j<3;j++) stageB(cur^1, k1, j);
    }

    const char* Ab = (const char*)(As0 + cur*16384);
    const char* Bb = (const char*)(Bs0 + cur*12288);

    short8 bf[3][2];
    #pragma unroll
    for (int nf=0;nf<3;nf++){
      const int row = wn*48 + nf*16 + l15;
      #pragma unroll
      for (int kk=0;kk<2;kk++)
        bf[nf][kk] = *(const short8*)(Bb + row*128 + ((kk*64 + g*16) ^ ((l15&7)<<4)));
    }

    #pragma unroll
    for (int ph=0; ph<4; ++ph){
      short8 af[2][2];
      #pragma unroll
      for (int i=0;i<2;i++){
        const int mf = ph*2 + i;
        const int row = wm*128 + mf*16 + l15;
        #pragma unroll
        for (int kk=0;kk<2;kk++)
          af[i][kk] = *(const short8*)(Ab + row*128 + ((kk*64 + g*16) ^ ((l15&7)<<4)));
      }
      asm volatile("s_waitcnt lgkmcnt(0)" ::: "memory");
      __builtin_amdgcn_sched_barrier(0);

      __builtin_amdgcn_s_setprio(1);
      #pragma unroll
      for (int i=0;i<2;i++)
        #pragma unroll
        for (int nf=0;nf<3;nf++)
          #pragma unroll
          for (int kk=0;kk<2;kk++)
            acc[ph*2+i][nf] = __builtin_amdgcn_mfma_f32_16x16x32_bf16(af[i][kk], bf[nf][kk],
                                                                      acc[ph*2+i][nf], 0, 0, 0);
      __builtin_amdgcn_s_setprio(0);
    }

    asm volatile("s_waitcnt vmcnt(0)" ::: "memory");
    __syncthreads();
    cur ^= 1;
  }

  // coalesced epilogue via LDS round-trip
  unsigned short* ct = lds;
  #pragma unroll
  for (int nf=0;nf<3;nf++){
    const int col = wn*48 + nf*16 + l15;
    const float bv = bias[n0 + col];
    #pragma unroll
    for (int mf=0;mf<8;mf++){
      #pragma unroll
      for (int r=0;r<4;r++)
        ct[(wm*128 + mf*16 + g*4 + r)*192 + col] = f2bf(acc[mf][nf][r] + bv);
    }
  }
  __syncthreads();
  #pragma unroll
  for (int u = 0; u < 12; ++u){
    const int idx = u*512 + tid;
    const int row = idx / 24, sl = idx % 24;
    *(short8*)(Cout + (size_t)(m0 + row) * N + n0 + sl*8) = *(const short8*)&ct[row*192 + sl*8];
  }
}

// ---------------- causal flash attention (R13/R16-exact, 48 us — DO NOT RESTRUCTURE) ----
__global__ __launch_bounds__(512) void attn_k(const unsigned short* __restrict__ qkv,
                                              unsigned short* __restrict__ aout)
{
  const int xy = ((int)blockIdx.x + (int)blockIdx.y) & 15;
  const int qb = blockIdx.z ? xy : (15 - xy);
  const int h = blockIdx.y, b = blockIdx.z;
  const int tid = threadIdx.x;
  const int w = tid >> 6, lane = tid & 63;
  const int l31 = lane & 31, hi = lane >> 5;
  const int qw = w >> 1, p = w & 1;

  __shared__ unsigned short lds[32768];
  unsigned short* Ksb = lds;
  unsigned short* Vsb = lds + 16384;

  const size_t rs = 3 * NXDIM;
  const unsigned short* Qg = qkv + (size_t)b * SS * rs + h * HDIM;
  const unsigned short* Kg = Qg + NXDIM;
  const unsigned short* Vg = Qg + 2 * NXDIM;

  const int q0w = qb*128 + qw*32;
  const int q   = q0w + l31;
  const int qw_hi = q0w + 31;

  short8 qf[4];
  #pragma unroll
  for (int c=0;c<4;c++)
    qf[c] = *(const short8*)(Qg + (size_t)q * rs + c*16 + 8*hi);

  f32x16 O0, O1;
  #pragma unroll
  for (int r=0;r<16;r++){ O0[r]=0.f; O1[r]=0.f; }
  float m_run = -1e30f, l_run = 0.f;
  const float SC2 = 0.125f * 1.44269504089f;
  const float THRR = 44.36f;

  const int krow_in = lane >> 3;
  const int kcol    = 8 * ((lane & 7) ^ (lane >> 3));
  const int v_d     = ((lane >> 3) & 3) * 16 + 8 * (lane & 1);
  const unsigned vtr_base = (unsigned)(size_t)Vsb + 8u*(unsigned)lane + 768u*(unsigned)hi;

  auto stage = [&](int bi, int tt){
    unsigned short* Kd = Ksb + (p*2 + bi)*4096;
    unsigned short* Vd = Vsb + (p*2 + bi)*4096;
    #pragma unroll
    for (int j=0;j<2;j++){
      const int ch = qw*2 + j;
      const int krow = tt*64 + ch*8 + krow_in;
      gload_lds16(Kg + (size_t)krow * rs + kcol, Kd + ch*512);
      const int vkv = tt*64 + (ch*2 + hi)*4 + ((lane>>1)&3);
      gload_lds16(Vg + (size_t)vkv * rs + v_d, Vd + ch*512);
    }
  };

  const int tmax = 2*qb + 1;
  stage(0, p);
  __syncthreads();
  int cur = 0;

  for (int t = p; t <= tmax; t += 2){
    if (t + 2 <= tmax) stage(cur^1, t+2);

    const char* Kb = (const char*)(Ksb + (p*2 + cur)*4096);
    const unsigned vb = vtr_base + (unsigned)((p*2 + cur)*8192);

    #pragma unroll
    for (int kvs=0;kvs<2;kvs++){
      const int kv_lo = t*64 + kvs*32;
      if (kv_lo > qw_hi) continue;

      f32x16 S;
      #pragma unroll
      for (int r=0;r<16;r++) S[r] = 0.f;
      __builtin_amdgcn_s_setprio(1);
      #pragma unroll
      for (int c=0;c<4;c++){
        const int row = kvs*32 + l31;
        short8 kf = *(const short8*)(Kb + row*128 + ((c*32 + 16*hi) ^ ((row&7)<<4)));
        S = __builtin_amdgcn_mfma_f32_32x32x16_bf16(kf, qf[c], S, 0, 0, 0);
      }
      __builtin_amdgcn_s_setprio(0);

      int2v tv[8];
      #pragma unroll
      for (int c=0;c<2;c++)
        #pragma unroll
        for (int dh=0;dh<2;dh++)
          #pragma unroll
          for (int eb=0;eb<2;eb++)
            tv[c*4+dh*2+eb] = ds_tr_b16(vb + (unsigned)((kvs*8 + c*4 + eb)*512 + dh*256));

      float mA=-1e30f, mB=-1e30f, mC=-1e30f, mD=-1e30f;
      if (kv_lo + 31 > q0w){
        #pragma unroll
        for (int r=0;r<16;r+=4){
          const int kvb = kv_lo + 8*(r>>2) + 4*hi;
          float s0 = (kvb+0 <= q) ? S[r+0] : -1e30f;
          float s1 = (kvb+1 <= q) ? S[r+1] : -1e30f;
          float s2 = (kvb+2 <= q) ? S[r+2] : -1e30f;
          float s3 = (kvb+3 <= q) ? S[r+3] : -1e30f;
          S[r+0]=s0; S[r+1]=s1; S[r+2]=s2; S[r+3]=s3;
          mA = fmaxf(mA, s0); mB = fmaxf(mB, s1); mC = fmaxf(mC, s2); mD = fmaxf(mD, s3);
        }
      } else {
        #pragma unroll
        for (int r=0;r<16;r+=4){
          mA = fmaxf(mA, S[r+0]); mB = fmaxf(mB, S[r+1]);
          mC = fmaxf(mC, S[r+2]); mD = fmaxf(mD, S[r+3]);
        }
      }
      float mx = fmaxf(fmaxf(mA,mB), fmaxf(mC,mD));
      mx = plmax(mx);

      if (!__all(mx <= m_run + THRR)){
        const float m_new = fmaxf(m_run, mx);
        const float corr = __builtin_exp2f((m_run - m_new) * SC2);
        m_run = m_new;
        l_run *= corr;
        #pragma unroll
        for (int r=0;r<16;r++){ O0[r] *= corr; O1[r] *= corr; }
      }
      const float msc = m_run * SC2;

      float lA=0.f, lB=0.f, lC=0.f, lD=0.f;
      #pragma unroll
      for (int r=0;r<16;r+=4){
        float p0=__builtin_exp2f(__builtin_fmaf(S[r+0],SC2,-msc));
        float p1=__builtin_exp2f(__builtin_fmaf(S[r+1],SC2,-msc));
        float p2=__builtin_exp2f(__builtin_fmaf(S[r+2],SC2,-msc));
        float p3=__builtin_exp2f(__builtin_fmaf(S[r+3],SC2,-msc));
        S[r+0]=p0; S[r+1]=p1; S[r+2]=p2; S[r+3]=p3;
        lA+=p0; lB+=p1; lC+=p2; lD+=p3;
      }
      float ls = (lA+lB) + (lC+lD);
      ls = pladd(ls);
      l_run += ls;

      unsigned pk[8];
      #pragma unroll
      for (int i=0;i<8;i++) pk[i] = cvt_pk_bf16(S[2*i], S[2*i+1]);
      short8 pfrag[2];
      #pragma unroll
      for (int c=0;c<2;c++){
        int2v r0 = plswap((int)pk[4*c+0], (int)pk[4*c+2]);
        int2v r1 = plswap((int)pk[4*c+1], (int)pk[4*c+3]);
        union { unsigned u[4]; short8 s; } pw;
        pw.u[0] = (unsigned)r0.x; pw.u[1] = (unsigned)r1.x;
        pw.u[2] = (unsigned)r0.y; pw.u[3] = (unsigned)r1.y;
        pfrag[c] = pw.s;
      }

      asm volatile("s_waitcnt lgkmcnt(0)" ::: "memory");
      __builtin_amdgcn_sched_barrier(0);

      __builtin_amdgcn_s_setprio(1);
      #pragma unroll
      for (int c=0;c<2;c++){
        union { int2v t[2]; short8 s; } v0, v1;
        v0.t[0] = tv[c*4+0]; v0.t[1] = tv[c*4+1];
        v1.t[0] = tv[c*4+2]; v1.t[1] = tv[c*4+3];
        O0 = __builtin_amdgcn_mfma_f32_32x32x16_bf16(v0.s, pfrag[c], O0, 0, 0, 0);
        O1 = __builtin_amdgcn_mfma_f32_32x32x16_bf16(v1.s, pfrag[c], O1, 0, 0, 0);
      }
      __builtin_amdgcn_s_setprio(0);
    }

    __syncthreads();
    cur ^= 1;
  }

  float* sm = (float*)lds + qw * (64*34);
  if (p){
    #pragma unroll
    for (int r=0;r<16;r++){ sm[lane*34 + r] = O0[r]; sm[lane*34 + 16 + r] = O1[r]; }
    sm[lane*34 + 32] = m_run;
    sm[lane*34 + 33] = l_run;
  }
  __syncthreads();
  if (!p){
    const float m1 = sm[lane*34 + 32], l1 = sm[lane*34 + 33];
    const float mm = fmaxf(m_run, m1);
    const float c0 = __builtin_exp2f((m_run - mm) * SC2);
    const float c1 = __builtin_exp2f((m1 - mm) * SC2);
    const float inv = 1.f / (l_run*c0 + l1*c1);
    unsigned short* dst = aout + ((size_t)b*SS + q) * NXDIM + h*HDIM;
    #pragma unroll
    for (int g4=0; g4<4; g4++){
      ushort4v a0, a1;
      #pragma unroll
      for (int i=0;i<4;i++){
        a0[i] = f2bf((O0[4*g4+i]*c0 + sm[lane*34 + 4*g4+i]*c1) * inv);
        a1[i] = f2bf((O1[4*g4+i]*c0 + sm[lane*34 + 16 + 4*g4+i]*c1) * inv);
      }
      *(ushort4v*)(dst + 8*g4 + 4*hi)      = a0;
      *(ushort4v*)(dst + 32 + 8*g4 + 4*hi) = a1;
    }
  }
}

extern "C" void kernel_launch(void* const* d_in, const int* in_sizes, int n_in,
                              void* d_out, int out_size, void* d_ws, size_t ws_size,
                              hipStream_t stream){
  (void)in_sizes; (void)n_in; (void)out_size; (void)ws_size;
  const float* x      = (const float*)d_in[0];   // [2,2048,1024]
  const float* w_attn = (const float*)d_in[1];   // [1024,3072]
  const float* b_attn = (const float*)d_in[2];   // [3072]
  const float* w_proj = (const float*)d_in[3];   // [1024,1024]
  const float* b_proj = (const float*)d_in[4];   // [1024]
  float* out = (float*)d_out;                    // [2,2048,1024] f32

  unsigned short* xb   = (unsigned short*)d_ws;              // 4096x1024 bf16
  unsigned short* waT  = xb  + (size_t)4096*1024;            // 3072x1024 bf16 (W_attn^T)
  unsigned short* wpT  = waT + (size_t)3072*1024;            // 1024x1024 bf16 (W_proj^T)
  unsigned short* qkv  = wpT + (size_t)1024*1024;            // 4096x3072 bf16
  unsigned short* aout = qkv + (size_t)4096*3072;            // 4096x1024 bf16

  prep_k<<<8192, 256, 0, stream>>>(x, xb, w_attn, waT, w_proj, wpT);
  gemm256_k<<<dim3(3072/192, 4096/256), 512, 0, stream>>>(xb, waT, b_attn, qkv, 4096, 3072, 1024);
  attn_k<<<dim3(SS/128, NHEADS, BB), 512, 0, stream>>>(qkv, aout);
  gemm2_64_k<<<dim3(1024/64, 4096/64), 256, 0, stream>>>(aout, wpT, b_proj, out, 4096, 1024, 1024);
}

// Round 21
// 105.215 us; speedup vs baseline: 1.0651x; 1.0206x over previous
//
#include <hip/hip_runtime.h>
#include <stdint.h>

typedef __attribute__((ext_vector_type(8))) short short8;
typedef __attribute__((ext_vector_type(4))) float f32x4;
typedef __attribute__((ext_vector_type(16))) float f32x16;
typedef __attribute__((ext_vector_type(4))) unsigned short ushort4v;
typedef __attribute__((ext_vector_type(2))) int int2v;

#define BB 2
#define SS 2048
#define NXDIM 1024
#define NHEADS 16
#define HDIM 64

__device__ __forceinline__ unsigned short f2bf(float f){
  unsigned int u = __float_as_uint(f);
  u += 0x7fffu + ((u >> 16) & 1u);
  return (unsigned short)(u >> 16);
}

__device__ __forceinline__ void gload_lds16(const void* g, void* l){
  __builtin_amdgcn_global_load_lds((const __attribute__((address_space(1))) void*)g,
                                   (__attribute__((address_space(3))) void*)l, 16, 0, 0);
}

__device__ __forceinline__ unsigned cvt_pk_bf16(float lo, float hi){
  unsigned r;
  asm("v_cvt_pk_bf16_f32 %0, %1, %2" : "=v"(r) : "v"(lo), "v"(hi));
  return r;
}

__device__ __forceinline__ int2v ds_tr_b16(unsigned addr){
  int2v r;
  asm volatile("ds_read_b64_tr_b16 %0, %1" : "=v"(r) : "v"(addr));
  return r;
}

// permlane32_swap (SSA builtin, no operand aliasing)
__device__ __forceinline__ int2v plswap(int a, int b){
  return __builtin_amdgcn_permlane32_swap(a, b, false, false);
}
__device__ __forceinline__ float plmax(float x){
  int2v r = plswap(__float_as_int(x), __float_as_int(x));
  return fmaxf(__int_as_float(r.x), __int_as_float(r.y));
}
__device__ __forceinline__ float pladd(float x){
  int2v r = plswap(__float_as_int(x), __float_as_int(x));
  return __int_as_float(r.x) + __int_as_float(r.y);
}

// ---------------- fused prep: x f32->bf16 + both weight transposes ----------------
__global__ __launch_bounds__(256) void prep_k(const float* __restrict__ x,
                                              unsigned short* __restrict__ xb,
                                              const float* __restrict__ wa,
                                              unsigned short* __restrict__ waT,
                                              const float* __restrict__ wp,
                                              unsigned short* __restrict__ wpT){
  __shared__ float t[32][33];
  int bid = blockIdx.x;
  if (bid < 4096){
    const int i = bid*256 + (int)threadIdx.x;
    float4 v = ((const float4*)x)[i];
    ushort4v r = { f2bf(v.x), f2bf(v.y), f2bf(v.z), f2bf(v.w) };
    ((ushort4v*)xb)[i] = r;
    return;
  }
  bid -= 4096;
  const int by = (bid >> 7) * 32;
  int bxi = bid & 127;
  const bool second = bxi >= 96;
  const float* in = second ? wp : wa;
  unsigned short* out = second ? wpT : waT;
  const int C = second ? 1024 : 3072;
  const int R = 1024;
  const int bx = (second ? (bxi - 96) : bxi) * 32;
  const int tx = threadIdx.x & 31, ty = threadIdx.x >> 5;
  #pragma unroll
  for (int i = ty; i < 32; i += 8)
    t[i][tx] = in[(size_t)(by + i) * C + bx + tx];
  __syncthreads();
  #pragma unroll
  for (int i = ty; i < 32; i += 8)
    out[(size_t)(bx + i) * R + by + tx] = f2bf(t[tx][i]);
}

// ---------------- bf16 GEMM 64² tile — gemm2, dbuf prefetch + XCD swizzle ----------
__global__ __launch_bounds__(256) void gemm2_64_k(const unsigned short* __restrict__ A,
                                                  const unsigned short* __restrict__ BT,
                                                  const float* __restrict__ bias,
                                                  float* __restrict__ Cout,
                                                  int M, int N, int K)
{
  __shared__ unsigned short As[2][64*32];
  __shared__ unsigned short Bs[2][64*32];
  const int tid = threadIdx.x;
  const int w = tid >> 6, lane = tid & 63;
  const int l15 = lane & 15, g = lane >> 4;
  const int wr = w >> 1, wc = w & 1;
  // T1 XCD-chunked swizzle: 1024 blocks, cpx=128 -> each XCD owns a contiguous chunk
  const int bid = (int)blockIdx.x + 16 * (int)blockIdx.y;
  const int swz = (bid & 7) * 128 + (bid >> 3);
  const int m0 = (swz >> 4) * 64, n0 = (swz & 15) * 64;

  f32x4 acc[2][2];
  #pragma unroll
  for (int m=0;m<2;m++)
    #pragma unroll
    for (int n=0;n<2;n++) acc[m][n] = (f32x4){0.f,0.f,0.f,0.f};

  const int srow_in = lane >> 2;
  const int scol = (lane & 3) * 8;

  auto stage = [&](int bi, int kt){
    const int k0 = kt * 32;
    gload_lds16(A  + (size_t)(m0 + w*16 + srow_in) * K + (k0 + scol), &As[bi][(w*16)*32]);
    gload_lds16(BT + (size_t)(n0 + w*16 + srow_in) * K + (k0 + scol), &Bs[bi][(w*16)*32]);
  };

  const int nt = K >> 5;
  stage(0, 0);
  __syncthreads();
  int cur = 0;

  for (int t = 0; t < nt; ++t){
    if (t + 1 < nt) stage(cur^1, t+1);

    short8 af[2], bf[2];
    #pragma unroll
    for (int m=0;m<2;m++) af[m] = *(const short8*)&As[cur][(wr*32 + m*16 + l15)*32 + g*8];
    #pragma unroll
    for (int n=0;n<2;n++) bf[n] = *(const short8*)&Bs[cur][(wc*32 + n*16 + l15)*32 + g*8];
    #pragma unroll
    for (int m=0;m<2;m++)
      #pragma unroll
      for (int n=0;n<2;n++)
        acc[m][n] = __builtin_amdgcn_mfma_f32_16x16x32_bf16(af[m], bf[n], acc[m][n], 0, 0, 0);

    __syncthreads();
    cur ^= 1;
  }

  const int crow0 = m0 + wr*32;
  const int ccol0 = n0 + wc*32;
  #pragma unroll
  for (int n=0;n<2;n++){
    const int col = ccol0 + n*16 + l15;
    const float bv = bias[col];
    #pragma unroll
    for (int m=0;m<2;m++){
      #pragma unroll
      for (int r=0;r<4;r++){
        const int row = crow0 + m*16 + g*4 + r;
        Cout[(size_t)row * N + col] = acc[m][n][r] + bv;
      }
    }
  }
}

// ---------------- bf16 GEMM 256x192, BK=64, 8 waves + XCD swizzle ----------------
__global__ __launch_bounds__(512) void gemm256_k(const unsigned short* __restrict__ A,
                                                 const unsigned short* __restrict__ BT,
                                                 const float* __restrict__ bias,
                                                 unsigned short* __restrict__ Cout,
                                                 int M, int N, int K)
{
  __shared__ unsigned short lds[57344];            // As[2][16384] | Bs[2][12288]
  unsigned short* As0 = lds;
  unsigned short* Bs0 = lds + 32768;
  const int tid = threadIdx.x;
  const int w = tid >> 6, lane = tid & 63;
  const int l15 = lane & 15, g = lane >> 4;
  const int wm = w >> 2, wn = w & 3;
  // T1 XCD-chunked swizzle: 256 blocks, cpx=32 -> XCD x owns m-rows {2x,2x+1}
  // (A panels L2-resident per XCD; fetched once per XCD instead of 16x).
  const int bid = (int)blockIdx.x + 16 * (int)blockIdx.y;
  const int swz = (bid & 7) * 32 + (bid >> 3);
  const int m0 = (swz >> 4) * 256, n0 = (swz & 15) * 192;

  f32x4 acc[8][3];
  #pragma unroll
  for (int m=0;m<8;m++)
    #pragma unroll
    for (int n=0;n<3;n++) acc[m][n] = (f32x4){0.f,0.f,0.f,0.f};

  const int srow = lane >> 3;
  const int scol = 8 * ((lane & 7) ^ (lane >> 3));

  auto stageA = [&](int bi, int k0, int j){
    const int r = w*32 + j*8 + srow;
    gload_lds16(A + (size_t)(m0 + r) * K + (k0 + scol), As0 + bi*16384 + (w*32 + j*8)*64);
  };
  auto stageB = [&](int bi, int k0, int j){
    const int r = w*24 + j*8 + srow;
    gload_lds16(BT + (size_t)(n0 + r) * K + (k0 + scol), Bs0 + bi*12288 + (w*24 + j*8)*64);
  };

  #pragma unroll
  for (int j=0;j<4;j++) stageA(0, 0, j);
  #pragma unroll
  for (int j=0;j<3;j++) stageB(0, 0, j);
  asm volatile("s_waitcnt vmcnt(0)" ::: "memory");
  __syncthreads();

  const int niter = K >> 6;
  int cur = 0;

  for (int t = 0; t < niter; ++t){
    const int k1 = (t+1) << 6;
    if (t+1 < niter){
      #pragma unroll
      for (int j=0;j<4;j++) stageA(cur^1, k1, j);
      #pragma unroll
      for (int j=0;j<3;j++) stageB(cur^1, k1, j);
    }

    const char* Ab = (const char*)(As0 + cur*16384);
    const char* Bb = (const char*)(Bs0 + cur*12288);

    short8 bf[3][2];
    #pragma unroll
    for (int nf=0;nf<3;nf++){
      const int row = wn*48 + nf*16 + l15;
      #pragma unroll
      for (int kk=0;kk<2;kk++)
        bf[nf][kk] = *(const short8*)(Bb + row*128 + ((kk*64 + g*16) ^ ((l15&7)<<4)));
    }

    #pragma unroll
    for (int ph=0; ph<4; ++ph){
      short8 af[2][2];
      #pragma unroll
      for (int i=0;i<2;i++){
        const int mf = ph*2 + i;
        const int row = wm*128 + mf*16 + l15;
        #pragma unroll
        for (int kk=0;kk<2;kk++)
          af[i][kk] = *(const short8*)(Ab + row*128 + ((kk*64 + g*16) ^ ((l15&7)<<4)));
      }
      asm volatile("s_waitcnt lgkmcnt(0)" ::: "memory");
      __builtin_amdgcn_sched_barrier(0);

      __builtin_amdgcn_s_setprio(1);
      #pragma unroll
      for (int i=0;i<2;i++)
        #pragma unroll
        for (int nf=0;nf<3;nf++)
          #pragma unroll
          for (int kk=0;kk<2;kk++)
            acc[ph*2+i][nf] = __builtin_amdgcn_mfma_f32_16x16x32_bf16(af[i][kk], bf[nf][kk],
                                                                      acc[ph*2+i][nf], 0, 0, 0);
      __builtin_amdgcn_s_setprio(0);
    }

    asm volatile("s_waitcnt vmcnt(0)" ::: "memory");
    __syncthreads();
    cur ^= 1;
  }

  // coalesced epilogue via LDS round-trip
  unsigned short* ct = lds;
  #pragma unroll
  for (int nf=0;nf<3;nf++){
    const int col = wn*48 + nf*16 + l15;
    const float bv = bias[n0 + col];
    #pragma unroll
    for (int mf=0;mf<8;mf++){
      #pragma unroll
      for (int r=0;r<4;r++)
        ct[(wm*128 + mf*16 + g*4 + r)*192 + col] = f2bf(acc[mf][nf][r] + bv);
    }
  }
  __syncthreads();
  #pragma unroll
  for (int u = 0; u < 12; ++u){
    const int idx = u*512 + tid;
    const int row = idx / 24, sl = idx % 24;
    *(short8*)(Cout + (size_t)(m0 + row) * N + n0 + sl*8) = *(const short8*)&ct[row*192 + sl*8];
  }
}

// ---------------- causal flash attention (R13/R16-exact, 48 us — DO NOT RESTRUCTURE) ----
__global__ __launch_bounds__(512) void attn_k(const unsigned short* __restrict__ qkv,
                                              unsigned short* __restrict__ aout)
{
  const int xy = ((int)blockIdx.x + (int)blockIdx.y) & 15;
  const int qb = blockIdx.z ? xy : (15 - xy);
  const int h = blockIdx.y, b = blockIdx.z;
  const int tid = threadIdx.x;
  const int w = tid >> 6, lane = tid & 63;
  const int l31 = lane & 31, hi = lane >> 5;
  const int qw = w >> 1, p = w & 1;

  __shared__ unsigned short lds[32768];
  unsigned short* Ksb = lds;
  unsigned short* Vsb = lds + 16384;

  const size_t rs = 3 * NXDIM;
  const unsigned short* Qg = qkv + (size_t)b * SS * rs + h * HDIM;
  const unsigned short* Kg = Qg + NXDIM;
  const unsigned short* Vg = Qg + 2 * NXDIM;

  const int q0w = qb*128 + qw*32;
  const int q   = q0w + l31;
  const int qw_hi = q0w + 31;

  short8 qf[4];
  #pragma unroll
  for (int c=0;c<4;c++)
    qf[c] = *(const short8*)(Qg + (size_t)q * rs + c*16 + 8*hi);

  f32x16 O0, O1;
  #pragma unroll
  for (int r=0;r<16;r++){ O0[r]=0.f; O1[r]=0.f; }
  float m_run = -1e30f, l_run = 0.f;
  const float SC2 = 0.125f * 1.44269504089f;
  const float THRR = 44.36f;

  const int krow_in = lane >> 3;
  const int kcol    = 8 * ((lane & 7) ^ (lane >> 3));
  const int v_d     = ((lane >> 3) & 3) * 16 + 8 * (lane & 1);
  const unsigned vtr_base = (unsigned)(size_t)Vsb + 8u*(unsigned)lane + 768u*(unsigned)hi;

  auto stage = [&](int bi, int tt){
    unsigned short* Kd = Ksb + (p*2 + bi)*4096;
    unsigned short* Vd = Vsb + (p*2 + bi)*4096;
    #pragma unroll
    for (int j=0;j<2;j++){
      const int ch = qw*2 + j;
      const int krow = tt*64 + ch*8 + krow_in;
      gload_lds16(Kg + (size_t)krow * rs + kcol, Kd + ch*512);
      const int vkv = tt*64 + (ch*2 + hi)*4 + ((lane>>1)&3);
      gload_lds16(Vg + (size_t)vkv * rs + v_d, Vd + ch*512);
    }
  };

  const int tmax = 2*qb + 1;
  stage(0, p);
  __syncthreads();
  int cur = 0;

  for (int t = p; t <= tmax; t += 2){
    if (t + 2 <= tmax) stage(cur^1, t+2);

    const char* Kb = (const char*)(Ksb + (p*2 + cur)*4096);
    const unsigned vb = vtr_base + (unsigned)((p*2 + cur)*8192);

    #pragma unroll
    for (int kvs=0;kvs<2;kvs++){
      const int kv_lo = t*64 + kvs*32;
      if (kv_lo > qw_hi) continue;

      f32x16 S;
      #pragma unroll
      for (int r=0;r<16;r++) S[r] = 0.f;
      __builtin_amdgcn_s_setprio(1);
      #pragma unroll
      for (int c=0;c<4;c++){
        const int row = kvs*32 + l31;
        short8 kf = *(const short8*)(Kb + row*128 + ((c*32 + 16*hi) ^ ((row&7)<<4)));
        S = __builtin_amdgcn_mfma_f32_32x32x16_bf16(kf, qf[c], S, 0, 0, 0);
      }
      __builtin_amdgcn_s_setprio(0);

      int2v tv[8];
      #pragma unroll
      for (int c=0;c<2;c++)
        #pragma unroll
        for (int dh=0;dh<2;dh++)
          #pragma unroll
          for (int eb=0;eb<2;eb++)
            tv[c*4+dh*2+eb] = ds_tr_b16(vb + (unsigned)((kvs*8 + c*4 + eb)*512 + dh*256));

      float mA=-1e30f, mB=-1e30f, mC=-1e30f, mD=-1e30f;
      if (kv_lo + 31 > q0w){
        #pragma unroll
        for (int r=0;r<16;r+=4){
          const int kvb = kv_lo + 8*(r>>2) + 4*hi;
          float s0 = (kvb+0 <= q) ? S[r+0] : -1e30f;
          float s1 = (kvb+1 <= q) ? S[r+1] : -1e30f;
          float s2 = (kvb+2 <= q) ? S[r+2] : -1e30f;
          float s3 = (kvb+3 <= q) ? S[r+3] : -1e30f;
          S[r+0]=s0; S[r+1]=s1; S[r+2]=s2; S[r+3]=s3;
          mA = fmaxf(mA, s0); mB = fmaxf(mB, s1); mC = fmaxf(mC, s2); mD = fmaxf(mD, s3);
        }
      } else {
        #pragma unroll
        for (int r=0;r<16;r+=4){
          mA = fmaxf(mA, S[r+0]); mB = fmaxf(mB, S[r+1]);
          mC = fmaxf(mC, S[r+2]); mD = fmaxf(mD, S[r+3]);
        }
      }
      float mx = fmaxf(fmaxf(mA,mB), fmaxf(mC,mD));
      mx = plmax(mx);

      if (!__all(mx <= m_run + THRR)){
        const float m_new = fmaxf(m_run, mx);
        const float corr = __builtin_exp2f((m_run - m_new) * SC2);
        m_run = m_new;
        l_run *= corr;
        #pragma unroll
        for (int r=0;r<16;r++){ O0[r] *= corr; O1[r] *= corr; }
      }
      const float msc = m_run * SC2;

      float lA=0.f, lB=0.f, lC=0.f, lD=0.f;
      #pragma unroll
      for (int r=0;r<16;r+=4){
        float p0=__builtin_exp2f(__builtin_fmaf(S[r+0],SC2,-msc));
        float p1=__builtin_exp2f(__builtin_fmaf(S[r+1],SC2,-msc));
        float p2=__builtin_exp2f(__builtin_fmaf(S[r+2],SC2,-msc));
        float p3=__builtin_exp2f(__builtin_fmaf(S[r+3],SC2,-msc));
        S[r+0]=p0; S[r+1]=p1; S[r+2]=p2; S[r+3]=p3;
        lA+=p0; lB+=p1; lC+=p2; lD+=p3;
      }
      float ls = (lA+lB) + (lC+lD);
      ls = pladd(ls);
      l_run += ls;

      unsigned pk[8];
      #pragma unroll
      for (int i=0;i<8;i++) pk[i] = cvt_pk_bf16(S[2*i], S[2*i+1]);
      short8 pfrag[2];
      #pragma unroll
      for (int c=0;c<2;c++){
        int2v r0 = plswap((int)pk[4*c+0], (int)pk[4*c+2]);
        int2v r1 = plswap((int)pk[4*c+1], (int)pk[4*c+3]);
        union { unsigned u[4]; short8 s; } pw;
        pw.u[0] = (unsigned)r0.x; pw.u[1] = (unsigned)r1.x;
        pw.u[2] = (unsigned)r0.y; pw.u[3] = (unsigned)r1.y;
        pfrag[c] = pw.s;
      }

      asm volatile("s_waitcnt lgkmcnt(0)" ::: "memory");
      __builtin_amdgcn_sched_barrier(0);

      __builtin_amdgcn_s_setprio(1);
      #pragma unroll
      for (int c=0;c<2;c++){
        union { int2v t[2]; short8 s; } v0, v1;
        v0.t[0] = tv[c*4+0]; v0.t[1] = tv[c*4+1];
        v1.t[0] = tv[c*4+2]; v1.t[1] = tv[c*4+3];
        O0 = __builtin_amdgcn_mfma_f32_32x32x16_bf16(v0.s, pfrag[c], O0, 0, 0, 0);
        O1 = __builtin_amdgcn_mfma_f32_32x32x16_bf16(v1.s, pfrag[c], O1, 0, 0, 0);
      }
      __builtin_amdgcn_s_setprio(0);
    }

    __syncthreads();
    cur ^= 1;
  }

  float* sm = (float*)lds + qw * (64*34);
  if (p){
    #pragma unroll
    for (int r=0;r<16;r++){ sm[lane*34 + r] = O0[r]; sm[lane*34 + 16 + r] = O1[r]; }
    sm[lane*34 + 32] = m_run;
    sm[lane*34 + 33] = l_run;
  }
  __syncthreads();
  if (!p){
    const float m1 = sm[lane*34 + 32], l1 = sm[lane*34 + 33];
    const float mm = fmaxf(m_run, m1);
    const float c0 = __builtin_exp2f((m_run - mm) * SC2);
    const float c1 = __builtin_exp2f((m1 - mm) * SC2);
    const float inv = 1.f / (l_run*c0 + l1*c1);
    unsigned short* dst = aout + ((size_t)b*SS + q) * NXDIM + h*HDIM;
    #pragma unroll
    for (int g4=0; g4<4; g4++){
      ushort4v a0, a1;
      #pragma unroll
      for (int i=0;i<4;i++){
        a0[i] = f2bf((O0[4*g4+i]*c0 + sm[lane*34 + 4*g4+i]*c1) * inv);
        a1[i] = f2bf((O1[4*g4+i]*c0 + sm[lane*34 + 16 + 4*g4+i]*c1) * inv);
      }
      *(ushort4v*)(dst + 8*g4 + 4*hi)      = a0;
      *(ushort4v*)(dst + 32 + 8*g4 + 4*hi) = a1;
    }
  }
}

extern "C" void kernel_launch(void* const* d_in, const int* in_sizes, int n_in,
                              void* d_out, int out_size, void* d_ws, size_t ws_size,
                              hipStream_t stream){
  (void)in_sizes; (void)n_in; (void)out_size; (void)ws_size;
  const float* x      = (const float*)d_in[0];   // [2,2048,1024]
  const float* w_attn = (const float*)d_in[1];   // [1024,3072]
  const float* b_attn = (const float*)d_in[2];   // [3072]
  const float* w_proj = (const float*)d_in[3];   // [1024,1024]
  const float* b_proj = (const float*)d_in[4];   // [1024]
  float* out = (float*)d_out;                    // [2,2048,1024] f32

  unsigned short* xb   = (unsigned short*)d_ws;              // 4096x1024 bf16
  unsigned short* waT  = xb  + (size_t)4096*1024;            // 3072x1024 bf16 (W_attn^T)
  unsigned short* wpT  = waT + (size_t)3072*1024;            // 1024x1024 bf16 (W_proj^T)
  unsigned short* qkv  = wpT + (size_t)1024*1024;            // 4096x3072 bf16
  unsigned short* aout = qkv + (size_t)4096*3072;            // 4096x1024 bf16

  prep_k<<<8192, 256, 0, stream>>>(x, xb, w_attn, waT, w_proj, wpT);
  gemm256_k<<<dim3(3072/192, 4096/256), 512, 0, stream>>>(xb, waT, b_attn, qkv, 4096, 3072, 1024);
  attn_k<<<dim3(SS/128, NHEADS, BB), 512, 0, stream>>>(qkv, aout);
  gemm2_64_k<<<dim3(1024/64, 4096/64), 256, 0, stream>>>(aout, wpT, b_proj, out, 4096, 1024, 1024);
}

// Round 22
// 105.175 us; speedup vs baseline: 1.0656x; 1.0004x over previous
//
#include <hip/hip_runtime.h>
#include <stdint.h>

typedef __attribute__((ext_vector_type(8))) short short8;
typedef __attribute__((ext_vector_type(4))) float f32x4;
typedef __attribute__((ext_vector_type(16))) float f32x16;
typedef __attribute__((ext_vector_type(4))) unsigned short ushort4v;
typedef __attribute__((ext_vector_type(2))) int int2v;

#define BB 2
#define SS 2048
#define NXDIM 1024
#define NHEADS 16
#define HDIM 64

__device__ __forceinline__ unsigned short f2bf(float f){
  unsigned int u = __float_as_uint(f);
  u += 0x7fffu + ((u >> 16) & 1u);
  return (unsigned short)(u >> 16);
}

__device__ __forceinline__ void gload_lds16(const void* g, void* l){
  __builtin_amdgcn_global_load_lds((const __attribute__((address_space(1))) void*)g,
                                   (__attribute__((address_space(3))) void*)l, 16, 0, 0);
}

__device__ __forceinline__ unsigned cvt_pk_bf16(float lo, float hi){
  unsigned r;
  asm("v_cvt_pk_bf16_f32 %0, %1, %2" : "=v"(r) : "v"(lo), "v"(hi));
  return r;
}

__device__ __forceinline__ int2v ds_tr_b16(unsigned addr){
  int2v r;
  asm volatile("ds_read_b64_tr_b16 %0, %1" : "=v"(r) : "v"(addr));
  return r;
}

// permlane32_swap (SSA builtin, no operand aliasing)
__device__ __forceinline__ int2v plswap(int a, int b){
  return __builtin_amdgcn_permlane32_swap(a, b, false, false);
}
__device__ __forceinline__ float plmax(float x){
  int2v r = plswap(__float_as_int(x), __float_as_int(x));
  return fmaxf(__int_as_float(r.x), __int_as_float(r.y));
}
__device__ __forceinline__ float pladd(float x){
  int2v r = plswap(__float_as_int(x), __float_as_int(x));
  return __int_as_float(r.x) + __int_as_float(r.y);
}

// ---------------- fused prep: x f32->bf16 + both weight transposes ----------------
__global__ __launch_bounds__(256) void prep_k(const float* __restrict__ x,
                                              unsigned short* __restrict__ xb,
                                              const float* __restrict__ wa,
                                              unsigned short* __restrict__ waT,
                                              const float* __restrict__ wp,
                                              unsigned short* __restrict__ wpT){
  __shared__ float t[32][33];
  int bid = blockIdx.x;
  if (bid < 4096){
    const int i = bid*256 + (int)threadIdx.x;
    float4 v = ((const float4*)x)[i];
    ushort4v r = { f2bf(v.x), f2bf(v.y), f2bf(v.z), f2bf(v.w) };
    ((ushort4v*)xb)[i] = r;
    return;
  }
  bid -= 4096;
  const int by = (bid >> 7) * 32;
  int bxi = bid & 127;
  const bool second = bxi >= 96;
  const float* in = second ? wp : wa;
  unsigned short* out = second ? wpT : waT;
  const int C = second ? 1024 : 3072;
  const int R = 1024;
  const int bx = (second ? (bxi - 96) : bxi) * 32;
  const int tx = threadIdx.x & 31, ty = threadIdx.x >> 5;
  #pragma unroll
  for (int i = ty; i < 32; i += 8)
    t[i][tx] = in[(size_t)(by + i) * C + bx + tx];
  __syncthreads();
  #pragma unroll
  for (int i = ty; i < 32; i += 8)
    out[(size_t)(bx + i) * R + by + tx] = f2bf(t[tx][i]);
}

// ---------------- bf16 GEMM 64² tile — gemm2, dbuf prefetch + XCD swizzle ----------
__global__ __launch_bounds__(256) void gemm2_64_k(const unsigned short* __restrict__ A,
                                                  const unsigned short* __restrict__ BT,
                                                  const float* __restrict__ bias,
                                                  float* __restrict__ Cout,
                                                  int M, int N, int K)
{
  __shared__ unsigned short As[2][64*32];
  __shared__ unsigned short Bs[2][64*32];
  const int tid = threadIdx.x;
  const int w = tid >> 6, lane = tid & 63;
  const int l15 = lane & 15, g = lane >> 4;
  const int wr = w >> 1, wc = w & 1;
  // T1 XCD-chunked swizzle: 1024 blocks, cpx=128 -> each XCD owns a contiguous chunk
  const int bid = (int)blockIdx.x + 16 * (int)blockIdx.y;
  const int swz = (bid & 7) * 128 + (bid >> 3);
  const int m0 = (swz >> 4) * 64, n0 = (swz & 15) * 64;

  f32x4 acc[2][2];
  #pragma unroll
  for (int m=0;m<2;m++)
    #pragma unroll
    for (int n=0;n<2;n++) acc[m][n] = (f32x4){0.f,0.f,0.f,0.f};

  const int srow_in = lane >> 2;
  const int scol = (lane & 3) * 8;

  auto stage = [&](int bi, int kt){
    const int k0 = kt * 32;
    gload_lds16(A  + (size_t)(m0 + w*16 + srow_in) * K + (k0 + scol), &As[bi][(w*16)*32]);
    gload_lds16(BT + (size_t)(n0 + w*16 + srow_in) * K + (k0 + scol), &Bs[bi][(w*16)*32]);
  };

  const int nt = K >> 5;
  stage(0, 0);
  __syncthreads();
  int cur = 0;

  for (int t = 0; t < nt; ++t){
    if (t + 1 < nt) stage(cur^1, t+1);

    short8 af[2], bf[2];
    #pragma unroll
    for (int m=0;m<2;m++) af[m] = *(const short8*)&As[cur][(wr*32 + m*16 + l15)*32 + g*8];
    #pragma unroll
    for (int n=0;n<2;n++) bf[n] = *(const short8*)&Bs[cur][(wc*32 + n*16 + l15)*32 + g*8];
    #pragma unroll
    for (int m=0;m<2;m++)
      #pragma unroll
      for (int n=0;n<2;n++)
        acc[m][n] = __builtin_amdgcn_mfma_f32_16x16x32_bf16(af[m], bf[n], acc[m][n], 0, 0, 0);

    __syncthreads();
    cur ^= 1;
  }

  const int crow0 = m0 + wr*32;
  const int ccol0 = n0 + wc*32;
  #pragma unroll
  for (int n=0;n<2;n++){
    const int col = ccol0 + n*16 + l15;
    const float bv = bias[col];
    #pragma unroll
    for (int m=0;m<2;m++){
      #pragma unroll
      for (int r=0;r<4;r++){
        const int row = crow0 + m*16 + g*4 + r;
        Cout[(size_t)row * N + col] = acc[m][n][r] + bv;
      }
    }
  }
}

// ---------------- bf16 GEMM 256x192, BK=64, 8 waves + XCD swizzle ----------------
__global__ __launch_bounds__(512) void gemm256_k(const unsigned short* __restrict__ A,
                                                 const unsigned short* __restrict__ BT,
                                                 const float* __restrict__ bias,
                                                 unsigned short* __restrict__ Cout,
                                                 int M, int N, int K)
{
  __shared__ unsigned short lds[57344];            // As[2][16384] | Bs[2][12288]
  unsigned short* As0 = lds;
  unsigned short* Bs0 = lds + 32768;
  const int tid = threadIdx.x;
  const int w = tid >> 6, lane = tid & 63;
  const int l15 = lane & 15, g = lane >> 4;
  const int wm = w >> 2, wn = w & 3;
  // T1 XCD-chunked swizzle: 256 blocks, cpx=32 -> XCD x owns m-rows {2x,2x+1}
  const int bid = (int)blockIdx.x + 16 * (int)blockIdx.y;
  const int swz = (bid & 7) * 32 + (bid >> 3);
  const int m0 = (swz >> 4) * 256, n0 = (swz & 15) * 192;

  f32x4 acc[8][3];
  #pragma unroll
  for (int m=0;m<8;m++)
    #pragma unroll
    for (int n=0;n<3;n++) acc[m][n] = (f32x4){0.f,0.f,0.f,0.f};

  const int srow = lane >> 3;
  const int scol = 8 * ((lane & 7) ^ (lane >> 3));

  auto stageA = [&](int bi, int k0, int j){
    const int r = w*32 + j*8 + srow;
    gload_lds16(A + (size_t)(m0 + r) * K + (k0 + scol), As0 + bi*16384 + (w*32 + j*8)*64);
  };
  auto stageB = [&](int bi, int k0, int j){
    const int r = w*24 + j*8 + srow;
    gload_lds16(BT + (size_t)(n0 + r) * K + (k0 + scol), Bs0 + bi*12288 + (w*24 + j*8)*64);
  };

  #pragma unroll
  for (int j=0;j<4;j++) stageA(0, 0, j);
  #pragma unroll
  for (int j=0;j<3;j++) stageB(0, 0, j);
  asm volatile("s_waitcnt vmcnt(0)" ::: "memory");
  __syncthreads();

  const int niter = K >> 6;
  int cur = 0;

  for (int t = 0; t < niter; ++t){
    const int k1 = (t+1) << 6;
    if (t+1 < niter){
      #pragma unroll
      for (int j=0;j<4;j++) stageA(cur^1, k1, j);
      #pragma unroll
      for (int j=0;j<3;j++) stageB(cur^1, k1, j);
    }

    const char* Ab = (const char*)(As0 + cur*16384);
    const char* Bb = (const char*)(Bs0 + cur*12288);

    short8 bf[3][2];
    #pragma unroll
    for (int nf=0;nf<3;nf++){
      const int row = wn*48 + nf*16 + l15;
      #pragma unroll
      for (int kk=0;kk<2;kk++)
        bf[nf][kk] = *(const short8*)(Bb + row*128 + ((kk*64 + g*16) ^ ((l15&7)<<4)));
    }

    #pragma unroll
    for (int ph=0; ph<4; ++ph){
      short8 af[2][2];
      #pragma unroll
      for (int i=0;i<2;i++){
        const int mf = ph*2 + i;
        const int row = wm*128 + mf*16 + l15;
        #pragma unroll
        for (int kk=0;kk<2;kk++)
          af[i][kk] = *(const short8*)(Ab + row*128 + ((kk*64 + g*16) ^ ((l15&7)<<4)));
      }
      asm volatile("s_waitcnt lgkmcnt(0)" ::: "memory");
      __builtin_amdgcn_sched_barrier(0);

      __builtin_amdgcn_s_setprio(1);
      #pragma unroll
      for (int i=0;i<2;i++)
        #pragma unroll
        for (int nf=0;nf<3;nf++)
          #pragma unroll
          for (int kk=0;kk<2;kk++)
            acc[ph*2+i][nf] = __builtin_amdgcn_mfma_f32_16x16x32_bf16(af[i][kk], bf[nf][kk],
                                                                      acc[ph*2+i][nf], 0, 0, 0);
      __builtin_amdgcn_s_setprio(0);
    }

    asm volatile("s_waitcnt vmcnt(0)" ::: "memory");
    __syncthreads();
    cur ^= 1;
  }

  // coalesced epilogue via LDS round-trip
  unsigned short* ct = lds;
  #pragma unroll
  for (int nf=0;nf<3;nf++){
    const int col = wn*48 + nf*16 + l15;
    const float bv = bias[n0 + col];
    #pragma unroll
    for (int mf=0;mf<8;mf++){
      #pragma unroll
      for (int r=0;r<4;r++)
        ct[(wm*128 + mf*16 + g*4 + r)*192 + col] = f2bf(acc[mf][nf][r] + bv);
    }
  }
  __syncthreads();
  #pragma unroll
  for (int u = 0; u < 12; ++u){
    const int idx = u*512 + tid;
    const int row = idx / 24, sl = idx % 24;
    *(short8*)(Cout + (size_t)(m0 + row) * N + n0 + sl*8) = *(const short8*)&ct[row*192 + sl*8];
  }
}

// ---------------- causal flash attention (R13-exact body + XCD-local head map) ----
// 512 thr = 8 waves = 4 q-waves x 2 kv-parities; QBLK=128; dbuf + prefetch.
// NEW: flat-id remap puts all 32 blocks (16 q-tiles x 2 batches) of 2 heads on one
// XCD -> K/V (2 MB) L2-resident per XCD. CU_j still gets f=j / f=j+256 = same
// (h,qt), batch flipped -> complementary-qb balance preserved.
__global__ __launch_bounds__(512) void attn_k(const unsigned short* __restrict__ qkv,
                                              unsigned short* __restrict__ aout)
{
  const int f = (int)blockIdx.x + 16*((int)blockIdx.y + 16*(int)blockIdx.z); // 0..511
  const int xcd = f & 7, idx = f >> 3;       // idx 0..63
  const int h  = xcd*2 + (idx & 1);          // 2 heads per XCD
  const int qt = (idx >> 1) & 15;
  const int b  = idx >> 5;
  const int xy = (qt + h) & 15;
  const int qb = b ? xy : (15 - xy);         // complementary pair on each CU
  const int tid = threadIdx.x;
  const int w = tid >> 6, lane = tid & 63;
  const int l31 = lane & 31, hi = lane >> 5;
  const int qw = w >> 1, p = w & 1;

  __shared__ unsigned short lds[32768];
  unsigned short* Ksb = lds;
  unsigned short* Vsb = lds + 16384;

  const size_t rs = 3 * NXDIM;
  const unsigned short* Qg = qkv + (size_t)b * SS * rs + h * HDIM;
  const unsigned short* Kg = Qg + NXDIM;
  const unsigned short* Vg = Qg + 2 * NXDIM;

  const int q0w = qb*128 + qw*32;
  const int q   = q0w + l31;
  const int qw_hi = q0w + 31;

  short8 qf[4];
  #pragma unroll
  for (int c=0;c<4;c++)
    qf[c] = *(const short8*)(Qg + (size_t)q * rs + c*16 + 8*hi);

  f32x16 O0, O1;
  #pragma unroll
  for (int r=0;r<16;r++){ O0[r]=0.f; O1[r]=0.f; }
  float m_run = -1e30f, l_run = 0.f;
  const float SC2 = 0.125f * 1.44269504089f;
  const float THRR = 44.36f;

  const int krow_in = lane >> 3;
  const int kcol    = 8 * ((lane & 7) ^ (lane >> 3));
  const int v_d     = ((lane >> 3) & 3) * 16 + 8 * (lane & 1);
  const unsigned vtr_base = (unsigned)(size_t)Vsb + 8u*(unsigned)lane + 768u*(unsigned)hi;

  auto stage = [&](int bi, int tt){
    unsigned short* Kd = Ksb + (p*2 + bi)*4096;
    unsigned short* Vd = Vsb + (p*2 + bi)*4096;
    #pragma unroll
    for (int j=0;j<2;j++){
      const int ch = qw*2 + j;
      const int krow = tt*64 + ch*8 + krow_in;
      gload_lds16(Kg + (size_t)krow * rs + kcol, Kd + ch*512);
      const int vkv = tt*64 + (ch*2 + hi)*4 + ((lane>>1)&3);
      gload_lds16(Vg + (size_t)vkv * rs + v_d, Vd + ch*512);
    }
  };

  const int tmax = 2*qb + 1;
  stage(0, p);
  __syncthreads();
  int cur = 0;

  for (int t = p; t <= tmax; t += 2){
    if (t + 2 <= tmax) stage(cur^1, t+2);

    const char* Kb = (const char*)(Ksb + (p*2 + cur)*4096);
    const unsigned vb = vtr_base + (unsigned)((p*2 + cur)*8192);

    #pragma unroll
    for (int kvs=0;kvs<2;kvs++){
      const int kv_lo = t*64 + kvs*32;
      if (kv_lo > qw_hi) continue;

      f32x16 S;
      #pragma unroll
      for (int r=0;r<16;r++) S[r] = 0.f;
      __builtin_amdgcn_s_setprio(1);
      #pragma unroll
      for (int c=0;c<4;c++){
        const int row = kvs*32 + l31;
        short8 kf = *(const short8*)(Kb + row*128 + ((c*32 + 16*hi) ^ ((row&7)<<4)));
        S = __builtin_amdgcn_mfma_f32_32x32x16_bf16(kf, qf[c], S, 0, 0, 0);
      }
      __builtin_amdgcn_s_setprio(0);

      int2v tv[8];
      #pragma unroll
      for (int c=0;c<2;c++)
        #pragma unroll
        for (int dh=0;dh<2;dh++)
          #pragma unroll
          for (int eb=0;eb<2;eb++)
            tv[c*4+dh*2+eb] = ds_tr_b16(vb + (unsigned)((kvs*8 + c*4 + eb)*512 + dh*256));

      float mA=-1e30f, mB=-1e30f, mC=-1e30f, mD=-1e30f;
      if (kv_lo + 31 > q0w){
        #pragma unroll
        for (int r=0;r<16;r+=4){
          const int kvb = kv_lo + 8*(r>>2) + 4*hi;
          float s0 = (kvb+0 <= q) ? S[r+0] : -1e30f;
          float s1 = (kvb+1 <= q) ? S[r+1] : -1e30f;
          float s2 = (kvb+2 <= q) ? S[r+2] : -1e30f;
          float s3 = (kvb+3 <= q) ? S[r+3] : -1e30f;
          S[r+0]=s0; S[r+1]=s1; S[r+2]=s2; S[r+3]=s3;
          mA = fmaxf(mA, s0); mB = fmaxf(mB, s1); mC = fmaxf(mC, s2); mD = fmaxf(mD, s3);
        }
      } else {
        #pragma unroll
        for (int r=0;r<16;r+=4){
          mA = fmaxf(mA, S[r+0]); mB = fmaxf(mB, S[r+1]);
          mC = fmaxf(mC, S[r+2]); mD = fmaxf(mD, S[r+3]);
        }
      }
      float mx = fmaxf(fmaxf(mA,mB), fmaxf(mC,mD));
      mx = plmax(mx);

      if (!__all(mx <= m_run + THRR)){
        const float m_new = fmaxf(m_run, mx);
        const float corr = __builtin_exp2f((m_run - m_new) * SC2);
        m_run = m_new;
        l_run *= corr;
        #pragma unroll
        for (int r=0;r<16;r++){ O0[r] *= corr; O1[r] *= corr; }
      }
      const float msc = m_run * SC2;

      float lA=0.f, lB=0.f, lC=0.f, lD=0.f;
      #pragma unroll
      for (int r=0;r<16;r+=4){
        float p0=__builtin_exp2f(__builtin_fmaf(S[r+0],SC2,-msc));
        float p1=__builtin_exp2f(__builtin_fmaf(S[r+1],SC2,-msc));
        float p2=__builtin_exp2f(__builtin_fmaf(S[r+2],SC2,-msc));
        float p3=__builtin_exp2f(__builtin_fmaf(S[r+3],SC2,-msc));
        S[r+0]=p0; S[r+1]=p1; S[r+2]=p2; S[r+3]=p3;
        lA+=p0; lB+=p1; lC+=p2; lD+=p3;
      }
      float ls = (lA+lB) + (lC+lD);
      ls = pladd(ls);
      l_run += ls;

      unsigned pk[8];
      #pragma unroll
      for (int i=0;i<8;i++) pk[i] = cvt_pk_bf16(S[2*i], S[2*i+1]);
      short8 pfrag[2];
      #pragma unroll
      for (int c=0;c<2;c++){
        int2v r0 = plswap((int)pk[4*c+0], (int)pk[4*c+2]);
        int2v r1 = plswap((int)pk[4*c+1], (int)pk[4*c+3]);
        union { unsigned u[4]; short8 s; } pw;
        pw.u[0] = (unsigned)r0.x; pw.u[1] = (unsigned)r1.x;
        pw.u[2] = (unsigned)r0.y; pw.u[3] = (unsigned)r1.y;
        pfrag[c] = pw.s;
      }

      asm volatile("s_waitcnt lgkmcnt(0)" ::: "memory");
      __builtin_amdgcn_sched_barrier(0);

      __builtin_amdgcn_s_setprio(1);
      #pragma unroll
      for (int c=0;c<2;c++){
        union { int2v t[2]; short8 s; } v0, v1;
        v0.t[0] = tv[c*4+0]; v0.t[1] = tv[c*4+1];
        v1.t[0] = tv[c*4+2]; v1.t[1] = tv[c*4+3];
        O0 = __builtin_amdgcn_mfma_f32_32x32x16_bf16(v0.s, pfrag[c], O0, 0, 0, 0);
        O1 = __builtin_amdgcn_mfma_f32_32x32x16_bf16(v1.s, pfrag[c], O1, 0, 0, 0);
      }
      __builtin_amdgcn_s_setprio(0);
    }

    __syncthreads();
    cur ^= 1;
  }

  float* sm = (float*)lds + qw * (64*34);
  if (p){
    #pragma unroll
    for (int r=0;r<16;r++){ sm[lane*34 + r] = O0[r]; sm[lane*34 + 16 + r] = O1[r]; }
    sm[lane*34 + 32] = m_run;
    sm[lane*34 + 33] = l_run;
  }
  __syncthreads();
  if (!p){
    const float m1 = sm[lane*34 + 32], l1 = sm[lane*34 + 33];
    const float mm = fmaxf(m_run, m1);
    const float c0 = __builtin_exp2f((m_run - mm) * SC2);
    const float c1 = __builtin_exp2f((m1 - mm) * SC2);
    const float inv = 1.f / (l_run*c0 + l1*c1);
    unsigned short* dst = aout + ((size_t)b*SS + q) * NXDIM + h*HDIM;
    #pragma unroll
    for (int g4=0; g4<4; g4++){
      ushort4v a0, a1;
      #pragma unroll
      for (int i=0;i<4;i++){
        a0[i] = f2bf((O0[4*g4+i]*c0 + sm[lane*34 + 4*g4+i]*c1) * inv);
        a1[i] = f2bf((O1[4*g4+i]*c0 + sm[lane*34 + 16 + 4*g4+i]*c1) * inv);
      }
      *(ushort4v*)(dst + 8*g4 + 4*hi)      = a0;
      *(ushort4v*)(dst + 32 + 8*g4 + 4*hi) = a1;
    }
  }
}

extern "C" void kernel_launch(void* const* d_in, const int* in_sizes, int n_in,
                              void* d_out, int out_size, void* d_ws, size_t ws_size,
                              hipStream_t stream){
  (void)in_sizes; (void)n_in; (void)out_size; (void)ws_size;
  const float* x      = (const float*)d_in[0];   // [2,2048,1024]
  const float* w_attn = (const float*)d_in[1];   // [1024,3072]
  const float* b_attn = (const float*)d_in[2];   // [3072]
  const float* w_proj = (const float*)d_in[3];   // [1024,1024]
  const float* b_proj = (const float*)d_in[4];   // [1024]
  float* out = (float*)d_out;                    // [2,2048,1024] f32

  unsigned short* xb   = (unsigned short*)d_ws;              // 4096x1024 bf16
  unsigned short* waT  = xb  + (size_t)4096*1024;            // 3072x1024 bf16 (W_attn^T)
  unsigned short* wpT  = waT + (size_t)3072*1024;            // 1024x1024 bf16 (W_proj^T)
  unsigned short* qkv  = wpT + (size_t)1024*1024;            // 4096x3072 bf16
  unsigned short* aout = qkv + (size_t)4096*3072;            // 4096x1024 bf16

  prep_k<<<8192, 256, 0, stream>>>(x, xb, w_attn, waT, w_proj, wpT);
  gemm256_k<<<dim3(3072/192, 4096/256), 512, 0, stream>>>(xb, waT, b_attn, qkv, 4096, 3072, 1024);
  attn_k<<<dim3(SS/128, NHEADS, BB), 512, 0, stream>>>(qkv, aout);
  gemm2_64_k<<<dim3(1024/64, 4096/64), 256, 0, stream>>>(aout, wpT, b_proj, out, 4096, 1024, 1024);
}